// Round 6
// baseline (466.127 us; speedup 1.0000x reference)
//
#include <hip/hip_runtime.h>

#define NN 4096
#define CAP 288          // nnz/row: mean 205, sd 13.9 -> +6 sd; dense fallback guards overflow
#define SLOPE 0.2f

typedef __attribute__((ext_vector_type(8))) short bf16x8;
typedef __attribute__((ext_vector_type(4))) float f32x4;

static __device__ __forceinline__ unsigned f2bf(float f) {   // RNE fp32->bf16 (low 16 bits)
  unsigned u = __builtin_bit_cast(unsigned, f);
  return (u + 0x7fffu + ((u >> 16) & 1u)) >> 16;
}
static __device__ __forceinline__ float bf2f(unsigned h) {
  return __builtin_bit_cast(float, h << 16);
}

// ---- workspace layout (float offsets unless noted) ----
#define V_OFF     0                        // v1i,v2i,v1s,v2s : 4*128
#define C_OFF     512                      // 4 score constants
#define BT_OFF    516                      // b_total[128]
#define S_OFF     1024                     // s1i,s2i,s1s,s2s : 4*4096
#define HXI_OFF   32768                    // Ld@x   [4096,128]
#define HXS_OFF   (HXI_OFF + NN*128)       // Lu@x
#define UI_OFF    (HXS_OFF + NN*128)       // x@Wi0 + Hxi@Wi1
#define US_OFF    (UI_OFF + NN*128)        // x@Ws0 + Hxs@Ws1
#define XWH_OFF   (US_OFF + NN*128)        // x@Wh (fp32)
#define OI_OFF    (XWH_OFF + NN*128)       // alpha_irr @ U_irr
#define OS_OFF    (OI_OFF + NN*128)        // alpha_sol @ U_sol
#define ZP_OFF    (OS_OFF + NN*128)        // P@xWh split-K partials: 8 * [4096,128]
#define WS_FLOATS (ZP_OFF + 8*NN*128)
// byte offsets past the float region:
#define JB_BYTE_OFF  ((size_t)WS_FLOATS * 4)                    // u32 col idx lists
#define VB_BYTE_OFF  (JB_BYTE_OFF  + (size_t)2*NN*CAP*4)        // f32 L values
#define EB_BYTE_OFF  (VB_BYTE_OFF  + (size_t)2*NN*CAP*4)        // f32 exp-scores
#define CNT_BYTE_OFF (EB_BYTE_OFF  + (size_t)2*NN*CAP*4)        // int counts 2*4096
#define XWTH_BYTE_OFF (CNT_BYTE_OFF + (size_t)2*NN*4)           // bf16 XwT hi [128][4096]
#define XWTL_BYTE_OFF (XWTH_BYTE_OFF + (size_t)128*NN*2)        // bf16 XwT lo
// total ws ≈ 62 MiB

// ---------------------------------------------------------------------------
// Prep: v-vectors so s1[i] = x[i,:]·v + c (x_irr never materialized), b_total.
__global__ __launch_bounds__(128) void k_prep(
    const float* __restrict__ Wi_w, const float* __restrict__ Wi_b,
    const float* __restrict__ Ws_w, const float* __restrict__ Ws_b,
    const float* __restrict__ Wh_b, const float* __restrict__ att_irr,
    const float* __restrict__ att_sol, float* __restrict__ ws) {
  const int t = threadIdx.x;  // one thread per input channel c
  float v1i = 0.f, v2i = 0.f, v1s = 0.f, v2s = 0.f;
  for (int j = 0; j < 2; ++j) {
    for (int o = 0; o < 128; ++o) {
      const float wi = Wi_w[j*16384 + t*128 + o];
      const float wv = Ws_w[j*16384 + t*128 + o];
      v1i += wi * att_irr[j*128 + o];
      v2i += wi * att_irr[256 + j*128 + o];
      v1s += wv * att_sol[j*128 + o];
      v2s += wv * att_sol[256 + j*128 + o];
    }
  }
  ws[V_OFF + t]       = v1i;
  ws[V_OFF + 128 + t] = v2i;
  ws[V_OFF + 256 + t] = v1s;
  ws[V_OFF + 384 + t] = v2s;
  ws[BT_OFF + t] = Wi_b[t] + Wi_b[128 + t] + Ws_b[t] + Ws_b[128 + t] + Wh_b[t];
  if (t < 4) {
    const float* bb = (t < 2) ? Wi_b : Ws_b;
    const float* aa = ((t < 2) ? att_irr : att_sol) + ((t & 1) ? 256 : 0);
    float c = 0.f;
    for (int k = 0; k < 256; ++k) c += bb[k] * aa[k];
    ws[C_OFF + t] = c;   // c1i, c2i, c1s, c2s
  }
}

// ---------------------------------------------------------------------------
__global__ __launch_bounds__(256) void k_scores(const float* __restrict__ x,
                                                float* __restrict__ ws) {
  const int wave = threadIdx.x >> 6, lane = threadIdx.x & 63;
  const int row = blockIdx.x * 4 + wave;
  const float* v = ws + V_OFF;
  const float x0 = x[row*128 + lane];
  const float x1 = x[row*128 + 64 + lane];
  float p0 = x0 * v[lane]       + x1 * v[64 + lane];
  float p1 = x0 * v[128 + lane] + x1 * v[192 + lane];
  float p2 = x0 * v[256 + lane] + x1 * v[320 + lane];
  float p3 = x0 * v[384 + lane] + x1 * v[448 + lane];
  #pragma unroll
  for (int off = 32; off; off >>= 1) {
    p0 += __shfl_down(p0, off);
    p1 += __shfl_down(p1, off);
    p2 += __shfl_down(p2, off);
    p3 += __shfl_down(p3, off);
  }
  if (lane == 0) {
    ws[S_OFF + row]          = p0 + ws[C_OFF + 0];  // s1_irr
    ws[S_OFF + NN + row]     = p1 + ws[C_OFF + 1];  // s2_irr
    ws[S_OFF + 2*NN + row]   = p2 + ws[C_OFF + 2];  // s1_sol
    ws[S_OFF + 3*NN + row]   = p3 + ws[C_OFF + 3];  // s2_sol
  }
}

// ---------------------------------------------------------------------------
__global__ __launch_bounds__(256) void k_zero(int* __restrict__ cnt) {
  cnt[blockIdx.x * 256 + threadIdx.x] = 0;   // grid 32 -> 8192 counters
}

// ---------------------------------------------------------------------------
// CSR build + exp-score fusion: one wave per quarter-row. 16 independent
// ballots, ONE global atomic per wave, scatter-store j(u32)/v/e.
__global__ __launch_bounds__(256) void k_csr(
    const float* __restrict__ Ld, const float* __restrict__ Lu,
    const float* __restrict__ ws, int* __restrict__ cntbuf,
    unsigned* __restrict__ jbuf, float* __restrict__ valb,
    float* __restrict__ eb) {
  const int lane = threadIdx.x & 63;
  const int W = __builtin_amdgcn_readfirstlane(blockIdx.x * 4 + (threadIdx.x >> 6));
  const int br = W >> 14;                    // 16384 quarter-chunks per matrix
  const int row = (W >> 2) & (NN - 1);
  const int quarter = W & 3;
  const float4* __restrict__ L4 =
      (const float4*)((br ? Lu : Ld) + (size_t)row * NN + quarter * 1024);
  const float s1 = ws[S_OFF + (br ? 2*NN : 0) + row];
  const float* __restrict__ s2a = ws + S_OFF + (br ? 3*NN : NN);
  float4 lv[4];
  #pragma unroll
  for (int i = 0; i < 4; ++i) lv[i] = L4[i*64 + lane];

  unsigned long long m[16];
  int runs[16];
  int run = 0;
  #pragma unroll
  for (int i = 0; i < 4; ++i)
    #pragma unroll
    for (int c = 0; c < 4; ++c) {
      const int r = i*4 + c;
      m[r] = __ballot((&lv[i].x)[c] != 0.f);
      runs[r] = run;
      run += (int)__popcll(m[r]);
    }
  int base = 0;
  if (lane == 0 && run) base = atomicAdd(&cntbuf[br*NN + row], run);
  base = __shfl(base, 0);
  const size_t rb = (size_t)(br*NN + row) * CAP;
  const unsigned long long lmask = (1ull << lane) - 1ull;
  #pragma unroll
  for (int i = 0; i < 4; ++i)
    #pragma unroll
    for (int c = 0; c < 4; ++c) {
      const int r = i*4 + c;
      const float v = (&lv[i].x)[c];
      if (v != 0.f) {
        const int pos = base + runs[r] + (int)__popcll(m[r] & lmask);
        if (pos < CAP) {
          const int jj = quarter*1024 + (i*64 + lane)*4 + c;
          jbuf[rb + pos] = (unsigned)jj;
          valb[rb + pos] = v;
          const float sc = s1 + s2a[jj];
          eb[rb + pos] = expf(sc >= 0.f ? sc : SLOPE * sc);
        }
      }
    }
}

// ---------------------------------------------------------------------------
// Hx = L@x per row. One wave per row. readfirstlane pins the row to an SGPR
// so list loads are scalar; each gather is global_load_dwordx2.
__global__ __launch_bounds__(256) void k_gather_hx(
    const float* __restrict__ Ld, const float* __restrict__ Lu,
    const float* __restrict__ x, float* __restrict__ ws,
    const unsigned* __restrict__ jbuf, const float* __restrict__ valb,
    const int* __restrict__ cntbuf) {
  const int lane = threadIdx.x & 63;
  const int W = __builtin_amdgcn_readfirstlane(blockIdx.x * 4 + (threadIdx.x >> 6));
  const int br = W >> 12;
  const int row = W & (NN - 1);
  const float2* __restrict__ x2 = (const float2*)x;
  float2* __restrict__ Hx2 = (float2*)(ws + (br ? HXS_OFF : HXI_OFF));
  const int cnt = cntbuf[br*NN + row];
  float a0 = 0.f, a1 = 0.f;
  if (cnt <= CAP) {
    const unsigned* __restrict__ jb = jbuf + (size_t)(br*NN + row) * CAP;
    const float* __restrict__ vb = valb + (size_t)(br*NN + row) * CAP;
    int p = 0;
    for (; p + 8 <= cnt; p += 8) {
      unsigned j[8]; float wv[8]; float2 g[8];
      #pragma unroll
      for (int i = 0; i < 8; ++i) { j[i] = jb[p+i]; wv[i] = vb[p+i]; }
      #pragma unroll
      for (int i = 0; i < 8; ++i) g[i] = x2[(size_t)j[i]*64 + lane];
      #pragma unroll
      for (int i = 0; i < 8; ++i) { a0 += wv[i]*g[i].x; a1 += wv[i]*g[i].y; }
    }
    for (; p < cnt; ++p) {
      const float2 g = x2[(size_t)jb[p]*64 + lane];
      a0 += vb[p]*g.x; a1 += vb[p]*g.y;
    }
  } else {   // overflow fallback: dense rescan (essentially never taken)
    const float* __restrict__ Lrow = (br ? Lu : Ld) + (size_t)row * NN;
    for (int j = 0; j < NN; ++j) {
      const float v = Lrow[j];
      if (v != 0.f) { const float2 g = x2[(size_t)j*64 + lane]; a0 += v*g.x; a1 += v*g.y; }
    }
  }
  float2 o; o.x = a0; o.y = a1;
  Hx2[row*64 + lane] = o;
}

// ---------------------------------------------------------------------------
// Small GEMMs: U_irr = x@Wi0 + Hxi@Wi1 ; U_sol = x@Ws0 + Hxs@Ws1 ; xWh = x@Wh.
__global__ __launch_bounds__(256) void k_ugemm(
    const float* __restrict__ x, const float* __restrict__ Wi_w,
    const float* __restrict__ Ws_w, const float* __restrict__ Wh_w,
    float* __restrict__ ws) {
  const int rb = blockIdx.x;       // 128 row-blocks of 32
  const int sel = blockIdx.y;      // 0:U_irr 1:U_sol 2:xWh
  const float* A[2]; const float* W[2]; int npass; float* out;
  if (sel == 0)      { A[0]=x; W[0]=Wi_w; A[1]=ws+HXI_OFF; W[1]=Wi_w+16384; npass=2; out=ws+UI_OFF; }
  else if (sel == 1) { A[0]=x; W[0]=Ws_w; A[1]=ws+HXS_OFF; W[1]=Ws_w+16384; npass=2; out=ws+US_OFF; }
  else               { A[0]=x; W[0]=Wh_w; A[1]=nullptr;    W[1]=nullptr;    npass=1; out=ws+XWH_OFF; }

  __shared__ __align__(16) float At[32][33];
  __shared__ __align__(16) float Wt[32][132];
  const int t = threadIdx.x;
  const int rg = t >> 4, cg = t & 15;
  const int r0 = rb * 32;
  float acc[2][8];
  #pragma unroll
  for (int i = 0; i < 2; ++i)
    #pragma unroll
    for (int j = 0; j < 8; ++j) acc[i][j] = 0.f;

  for (int ps = 0; ps < npass; ++ps) {
    const float* __restrict__ Ap = A[ps];
    const float* __restrict__ Wp = W[ps];
    for (int k0 = 0; k0 < 128; k0 += 32) {
      __syncthreads();
      { const int row = t >> 3, kq = t & 7;
        const float4 av = *(const float4*)&Ap[(r0 + row)*128 + k0 + kq*4];
        At[row][kq*4+0] = av.x; At[row][kq*4+1] = av.y;
        At[row][kq*4+2] = av.z; At[row][kq*4+3] = av.w; }
      #pragma unroll
      for (int l = 0; l < 4; ++l) {
        const int idx = t + l*256;
        const int kr = idx >> 5, c4 = idx & 31;
        const float4 wv = *(const float4*)&Wp[(k0 + kr)*128 + c4*4];
        Wt[kr][c4*4+0] = wv.x; Wt[kr][c4*4+1] = wv.y;
        Wt[kr][c4*4+2] = wv.z; Wt[kr][c4*4+3] = wv.w;
      }
      __syncthreads();
      #pragma unroll
      for (int k = 0; k < 32; ++k) {
        const float a0 = At[rg*2 + 0][k];
        const float a1 = At[rg*2 + 1][k];
        const float4 b0 = *(const float4*)&Wt[k][cg*8];
        const float4 b1 = *(const float4*)&Wt[k][cg*8 + 4];
        acc[0][0] += a0*b0.x; acc[0][1] += a0*b0.y; acc[0][2] += a0*b0.z; acc[0][3] += a0*b0.w;
        acc[0][4] += a0*b1.x; acc[0][5] += a0*b1.y; acc[0][6] += a0*b1.z; acc[0][7] += a0*b1.w;
        acc[1][0] += a1*b0.x; acc[1][1] += a1*b0.y; acc[1][2] += a1*b0.z; acc[1][3] += a1*b0.w;
        acc[1][4] += a1*b1.x; acc[1][5] += a1*b1.y; acc[1][6] += a1*b1.z; acc[1][7] += a1*b1.w;
      }
    }
  }
  #pragma unroll
  for (int i = 0; i < 2; ++i) {
    const int r = r0 + rg*2 + i;
    #pragma unroll
    for (int j = 0; j < 8; ++j) out[r*128 + cg*8 + j] = acc[i][j];
  }
}

// ---------------------------------------------------------------------------
// Transpose xWh (fp32 [4096k][128n]) -> XwT hi/lo bf16 [128n][4096k].
__global__ __launch_bounds__(256) void k_xwt(const float* __restrict__ ws,
                                             unsigned short* __restrict__ XwTh,
                                             unsigned short* __restrict__ XwTl) {
  const float* __restrict__ Xw = ws + XWH_OFF;
  __shared__ float tile[64][133];
  const int t = threadIdx.x;
  const int k0 = blockIdx.x * 64;
  #pragma unroll
  for (int lp = 0; lp < 8; ++lp) {
    const int idx = t + lp*256;           // 2048 float4s = 64x128 floats
    const int r = idx >> 5, c4 = idx & 31;
    const float4 v = *(const float4*)&Xw[(size_t)(k0 + r)*128 + c4*4];
    tile[r][c4*4+0]=v.x; tile[r][c4*4+1]=v.y; tile[r][c4*4+2]=v.z; tile[r][c4*4+3]=v.w;
  }
  __syncthreads();
  const int n = t >> 1, seg = t & 1;
  unsigned oh[16], ol[16];
  #pragma unroll
  for (int q = 0; q < 16; ++q) {
    const int kk = seg*32 + q*2;
    const float f0 = tile[kk][n], f1 = tile[kk+1][n];
    const unsigned h0 = f2bf(f0), h1 = f2bf(f1);
    const unsigned l0 = f2bf(f0 - bf2f(h0)), l1 = f2bf(f1 - bf2f(h1));
    oh[q] = h0 | (h1 << 16);
    ol[q] = l0 | (l1 << 16);
  }
  unsigned* __restrict__ dh = (unsigned*)&XwTh[(size_t)n*NN + k0 + seg*32];
  unsigned* __restrict__ dl = (unsigned*)&XwTl[(size_t)n*NN + k0 + seg*32];
  #pragma unroll
  for (int q = 0; q < 16; ++q) { dh[q] = oh[q]; dl[q] = ol[q]; }
}

// ---------------------------------------------------------------------------
// Dense P @ xWh on matrix cores, 3-term bf16 split. Retiled for occupancy:
// block = 16 rows x 128 cols, 4 waves (wave = 16 rows x 32 cols, nt=2).
// Grid (256, 8) = 2048 blocks = 8 blocks/CU = 32 waves/CU (vs 8 before).
// __launch_bounds__(256,8) pins VGPR <= 64 to stay above the occupancy cliff.
__global__ __launch_bounds__(256, 8) void k_pgemm(const float* __restrict__ P,
                                               const unsigned short* __restrict__ XwTh,
                                               const unsigned short* __restrict__ XwTl,
                                               float* __restrict__ zpart) {
  const int t = threadIdx.x;
  const int w = t >> 6, l = t & 63;       // w = col-group (0..3)
  const int quad = l >> 4, m16 = l & 15;
  const int r0 = blockIdx.x * 16;         // 256 row-blocks of 16
  const int kz = blockIdx.y;              // 8 K-splits of 512
  const float* __restrict__ Arow = P + (size_t)(r0 + m16) * NN;
  const int kbase = kz * 512;

  f32x4 acc[2];
  acc[0] = (f32x4){0.f, 0.f, 0.f, 0.f};
  acc[1] = (f32x4){0.f, 0.f, 0.f, 0.f};

  for (int ks = 0; ks < 16; ++ks) {
    const int k0 = kbase + ks*32;
    const float4 a0 = *(const float4*)&Arow[k0 + quad*8];
    const float4 a1 = *(const float4*)&Arow[k0 + quad*8 + 4];
    bf16x8 bh[2], bl[2];
    #pragma unroll
    for (int nt = 0; nt < 2; ++nt) {
      const size_t cb = (size_t)(w*32 + nt*16 + m16) * NN + k0 + quad*8;
      bh[nt] = *(const bf16x8*)&XwTh[cb];
      bl[nt] = *(const bf16x8*)&XwTl[cb];
    }
    bf16x8 ah, al;
    #pragma unroll
    for (int c = 0; c < 4; ++c) {
      const float f0 = (&a0.x)[c], f1 = (&a1.x)[c];
      const unsigned h0 = f2bf(f0), h1 = f2bf(f1);
      ah[c]   = (short)h0; ah[c+4] = (short)h1;
      al[c]   = (short)f2bf(f0 - bf2f(h0));
      al[c+4] = (short)f2bf(f1 - bf2f(h1));
    }
    #pragma unroll
    for (int nt = 0; nt < 2; ++nt) {
      acc[nt] = __builtin_amdgcn_mfma_f32_16x16x32_bf16(ah, bh[nt], acc[nt], 0, 0, 0);
      acc[nt] = __builtin_amdgcn_mfma_f32_16x16x32_bf16(al, bh[nt], acc[nt], 0, 0, 0);
      acc[nt] = __builtin_amdgcn_mfma_f32_16x16x32_bf16(ah, bl[nt], acc[nt], 0, 0, 0);
    }
  }
  float* __restrict__ zp = zpart + (size_t)kz * NN * 128;
  // C/D layout: col = lane&15, row = quad*4 + reg  [verified m89/m91]
  #pragma unroll
  for (int nt = 0; nt < 2; ++nt)
    #pragma unroll
    for (int r = 0; r < 4; ++r)
      zp[(size_t)(r0 + quad*4 + r)*128 + w*32 + nt*16 + m16] = acc[nt][r];
}

// ---------------------------------------------------------------------------
// Attention: one wave per (row,branch). Scalar-load (j,e) lists, denominator
// accumulated in-register, 8 independent U-gathers in flight.
__global__ __launch_bounds__(256) void k_attn(
    const float* __restrict__ Ld, const float* __restrict__ Lu,
    float* __restrict__ ws, const unsigned* __restrict__ jbuf,
    const float* __restrict__ eb, const int* __restrict__ cntbuf) {
  const int lane = threadIdx.x & 63;
  const int W = __builtin_amdgcn_readfirstlane(blockIdx.x * 4 + (threadIdx.x >> 6));
  const int br = W >> 12;
  const int row = W & (NN - 1);
  const float2* __restrict__ U2 = (const float2*)(ws + (br ? US_OFF : UI_OFF));
  float2* __restrict__ O2 = (float2*)(ws + (br ? OS_OFF : OI_OFF));
  const int cnt = cntbuf[br*NN + row];
  float a0 = 0.f, a1 = 0.f, den = 0.f;

  if (cnt > 0 && cnt <= CAP) {
    const unsigned* __restrict__ jb = jbuf + (size_t)(br*NN + row) * CAP;
    const float* __restrict__ el = eb + (size_t)(br*NN + row) * CAP;
    int p = 0;
    for (; p + 8 <= cnt; p += 8) {
      unsigned j[8]; float e[8]; float2 g[8];
      #pragma unroll
      for (int i = 0; i < 8; ++i) { j[i] = jb[p+i]; e[i] = el[p+i]; }
      #pragma unroll
      for (int i = 0; i < 8; ++i) g[i] = U2[(size_t)j[i]*64 + lane];
      #pragma unroll
      for (int i = 0; i < 8; ++i) { a0 += e[i]*g[i].x; a1 += e[i]*g[i].y; den += e[i]; }
    }
    for (; p < cnt; ++p) {
      const float2 g = U2[(size_t)jb[p]*64 + lane];
      a0 += el[p]*g.x; a1 += el[p]*g.y; den += el[p];
    }
    float2 o; o.x = a0 / den; o.y = a1 / den;
    O2[row*64 + lane] = o;
  } else if (cnt == 0) {
    // all-masked row -> uniform softmax (never taken at 5% density)
    for (int j = 0; j < NN; ++j) { const float2 g = U2[(size_t)j*64 + lane]; a0 += g.x; a1 += g.y; }
    float2 o; o.x = a0 * (1.f/NN); o.y = a1 * (1.f/NN);
    O2[row*64 + lane] = o;
  } else {
    // list overflow fallback: dense rescan with on-the-fly scores
    const float s1 = ws[S_OFF + (br ? 2*NN : 0) + row];
    const float* __restrict__ s2a = ws + S_OFF + (br ? 3*NN : NN);
    const float* __restrict__ Lrow = (br ? Lu : Ld) + (size_t)row * NN;
    for (int j = 0; j < NN; ++j) {
      const float v = Lrow[j];
      if (v != 0.f) {
        const float sc = s1 + s2a[j];
        const float e = expf(sc >= 0.f ? sc : SLOPE * sc);
        const float2 g = U2[(size_t)j*64 + lane];
        a0 += e*g.x; a1 += e*g.y; den += e;
      }
    }
    float2 o; o.x = a0 / den; o.y = a1 / den;
    O2[row*64 + lane] = o;
  }
}

// ---------------------------------------------------------------------------
// z = O_irr + O_sol + sum_k zpart[k] + b_total
__global__ __launch_bounds__(256) void k_combine(const float* __restrict__ ws,
                                                 float* __restrict__ z) {
  const int i = blockIdx.x * 256 + threadIdx.x;
  const int col = i & 127;
  float acc = ws[BT_OFF + col] + ws[OI_OFF + i] + ws[OS_OFF + i];
  #pragma unroll
  for (int kz = 0; kz < 8; ++kz) acc += ws[ZP_OFF + kz*NN*128 + i];
  z[i] = acc;
}

// ---------------------------------------------------------------------------
extern "C" void kernel_launch(void* const* d_in, const int* in_sizes, int n_in,
                              void* d_out, int out_size, void* d_ws, size_t ws_size,
                              hipStream_t stream) {
  const float* x       = (const float*)d_in[0];
  const float* Lu      = (const float*)d_in[1];
  const float* Ld      = (const float*)d_in[2];
  const float* P       = (const float*)d_in[3];
  const float* Wi_w    = (const float*)d_in[4];
  const float* Wi_b    = (const float*)d_in[5];
  const float* Ws_w    = (const float*)d_in[6];
  const float* Ws_b    = (const float*)d_in[7];
  const float* Wh_w    = (const float*)d_in[8];
  const float* Wh_b    = (const float*)d_in[9];
  const float* att_irr = (const float*)d_in[10];
  const float* att_sol = (const float*)d_in[11];
  float* z  = (float*)d_out;
  float* ws = (float*)d_ws;
  unsigned*       jbuf = (unsigned*)((char*)d_ws + JB_BYTE_OFF);
  float*          valb = (float*)((char*)d_ws + VB_BYTE_OFF);
  float*          ebuf = (float*)((char*)d_ws + EB_BYTE_OFF);
  int*            cntb = (int*)((char*)d_ws + CNT_BYTE_OFF);
  unsigned short* xwth = (unsigned short*)((char*)d_ws + XWTH_BYTE_OFF);
  unsigned short* xwtl = (unsigned short*)((char*)d_ws + XWTL_BYTE_OFF);

  k_prep<<<1, 128, 0, stream>>>(Wi_w, Wi_b, Ws_w, Ws_b, Wh_b, att_irr, att_sol, ws);
  k_scores<<<1024, 256, 0, stream>>>(x, ws);
  k_zero<<<32, 256, 0, stream>>>(cntb);
  k_csr<<<8192, 256, 0, stream>>>(Ld, Lu, ws, cntb, jbuf, valb, ebuf);
  k_gather_hx<<<2048, 256, 0, stream>>>(Ld, Lu, x, ws, jbuf, valb, cntb);
  {
    dim3 g(128, 3);
    k_ugemm<<<g, 256, 0, stream>>>(x, Wi_w, Ws_w, Wh_w, ws);
  }
  k_xwt<<<64, 256, 0, stream>>>(ws, xwth, xwtl);
  {
    dim3 g(256, 8);
    k_pgemm<<<g, 256, 0, stream>>>(P, xwth, xwtl, ws + ZP_OFF);
  }
  k_attn<<<2048, 256, 0, stream>>>(Ld, Lu, ws, jbuf, ebuf, cntb);
  k_combine<<<NN * 128 / 256, 256, 0, stream>>>(ws, z);
}

// Round 7
// 413.005 us; speedup vs baseline: 1.1286x; 1.1286x over previous
//
#include <hip/hip_runtime.h>

#define NN 4096
#define CAP 288          // nnz/row: mean 205, sd 13.9 -> +6 sd; dense fallback guards overflow
#define SLOPE 0.2f

typedef __attribute__((ext_vector_type(8))) short bf16x8;
typedef __attribute__((ext_vector_type(4))) float f32x4;

static __device__ __forceinline__ unsigned f2bf(float f) {   // RNE fp32->bf16 (low 16 bits)
  unsigned u = __builtin_bit_cast(unsigned, f);
  return (u + 0x7fffu + ((u >> 16) & 1u)) >> 16;
}
static __device__ __forceinline__ float bf2f(unsigned h) {
  return __builtin_bit_cast(float, h << 16);
}

// ---- workspace layout (float offsets unless noted) ----
#define V_OFF     0                        // v1i,v2i,v1s,v2s : 4*128
#define C_OFF     512                      // 4 score constants
#define BT_OFF    516                      // b_total[128]
#define S_OFF     1024                     // s1i,s2i,s1s,s2s : 4*4096
#define HXI_OFF   32768                    // Ld@x   [4096,128]
#define HXS_OFF   (HXI_OFF + NN*128)       // Lu@x
#define UI_OFF    (HXS_OFF + NN*128)       // x@Wi0 + Hxi@Wi1
#define US_OFF    (UI_OFF + NN*128)        // x@Ws0 + Hxs@Ws1
#define XWH_OFF   (US_OFF + NN*128)        // x@Wh (fp32)
#define OI_OFF    (XWH_OFF + NN*128)       // alpha_irr @ U_irr
#define OS_OFF    (OI_OFF + NN*128)        // alpha_sol @ U_sol
#define ZP_OFF    (OS_OFF + NN*128)        // P@xWh split-K partials: 8 * [4096,128]
#define WS_FLOATS (ZP_OFF + 8*NN*128)
// byte offsets past the float region:
#define JB_BYTE_OFF  ((size_t)WS_FLOATS * 4)                    // u32 col idx lists
#define VB_BYTE_OFF  (JB_BYTE_OFF  + (size_t)2*NN*CAP*4)        // f32 L values
#define EB_BYTE_OFF  (VB_BYTE_OFF  + (size_t)2*NN*CAP*4)        // f32 exp-scores
#define CNT_BYTE_OFF (EB_BYTE_OFF  + (size_t)2*NN*CAP*4)        // int counts 2*4096
#define BPH_BYTE_OFF (CNT_BYTE_OFF + (size_t)2*NN*4)            // bf16 Bpack hi [512f][128n][8]
#define BPL_BYTE_OFF (BPH_BYTE_OFF + (size_t)512*128*16)        // bf16 Bpack lo
// total ws ≈ 62 MiB

// ---------------------------------------------------------------------------
// Prep: v-vectors so s1[i] = x[i,:]·v + c (x_irr never materialized), b_total.
__global__ __launch_bounds__(128) void k_prep(
    const float* __restrict__ Wi_w, const float* __restrict__ Wi_b,
    const float* __restrict__ Ws_w, const float* __restrict__ Ws_b,
    const float* __restrict__ Wh_b, const float* __restrict__ att_irr,
    const float* __restrict__ att_sol, float* __restrict__ ws) {
  const int t = threadIdx.x;  // one thread per input channel c
  float v1i = 0.f, v2i = 0.f, v1s = 0.f, v2s = 0.f;
  for (int j = 0; j < 2; ++j) {
    for (int o = 0; o < 128; ++o) {
      const float wi = Wi_w[j*16384 + t*128 + o];
      const float wv = Ws_w[j*16384 + t*128 + o];
      v1i += wi * att_irr[j*128 + o];
      v2i += wi * att_irr[256 + j*128 + o];
      v1s += wv * att_sol[j*128 + o];
      v2s += wv * att_sol[256 + j*128 + o];
    }
  }
  ws[V_OFF + t]       = v1i;
  ws[V_OFF + 128 + t] = v2i;
  ws[V_OFF + 256 + t] = v1s;
  ws[V_OFF + 384 + t] = v2s;
  ws[BT_OFF + t] = Wi_b[t] + Wi_b[128 + t] + Ws_b[t] + Ws_b[128 + t] + Wh_b[t];
  if (t < 4) {
    const float* bb = (t < 2) ? Wi_b : Ws_b;
    const float* aa = ((t < 2) ? att_irr : att_sol) + ((t & 1) ? 256 : 0);
    float c = 0.f;
    for (int k = 0; k < 256; ++k) c += bb[k] * aa[k];
    ws[C_OFF + t] = c;   // c1i, c2i, c1s, c2s
  }
}

// ---------------------------------------------------------------------------
__global__ __launch_bounds__(256) void k_scores(const float* __restrict__ x,
                                                float* __restrict__ ws) {
  const int wave = threadIdx.x >> 6, lane = threadIdx.x & 63;
  const int row = blockIdx.x * 4 + wave;
  const float* v = ws + V_OFF;
  const float x0 = x[row*128 + lane];
  const float x1 = x[row*128 + 64 + lane];
  float p0 = x0 * v[lane]       + x1 * v[64 + lane];
  float p1 = x0 * v[128 + lane] + x1 * v[192 + lane];
  float p2 = x0 * v[256 + lane] + x1 * v[320 + lane];
  float p3 = x0 * v[384 + lane] + x1 * v[448 + lane];
  #pragma unroll
  for (int off = 32; off; off >>= 1) {
    p0 += __shfl_down(p0, off);
    p1 += __shfl_down(p1, off);
    p2 += __shfl_down(p2, off);
    p3 += __shfl_down(p3, off);
  }
  if (lane == 0) {
    ws[S_OFF + row]          = p0 + ws[C_OFF + 0];  // s1_irr
    ws[S_OFF + NN + row]     = p1 + ws[C_OFF + 1];  // s2_irr
    ws[S_OFF + 2*NN + row]   = p2 + ws[C_OFF + 2];  // s1_sol
    ws[S_OFF + 3*NN + row]   = p3 + ws[C_OFF + 3];  // s2_sol
  }
}

// ---------------------------------------------------------------------------
__global__ __launch_bounds__(256) void k_zero(int* __restrict__ cnt) {
  cnt[blockIdx.x * 256 + threadIdx.x] = 0;   // grid 32 -> 8192 counters
}

// ---------------------------------------------------------------------------
// CSR build + exp-score fusion: one wave per quarter-row. 16 independent
// ballots, ONE global atomic per wave, scatter-store j(u32)/v/e.
__global__ __launch_bounds__(256) void k_csr(
    const float* __restrict__ Ld, const float* __restrict__ Lu,
    const float* __restrict__ ws, int* __restrict__ cntbuf,
    unsigned* __restrict__ jbuf, float* __restrict__ valb,
    float* __restrict__ eb) {
  const int lane = threadIdx.x & 63;
  const int W = __builtin_amdgcn_readfirstlane(blockIdx.x * 4 + (threadIdx.x >> 6));
  const int br = W >> 14;                    // 16384 quarter-chunks per matrix
  const int row = (W >> 2) & (NN - 1);
  const int quarter = W & 3;
  const float4* __restrict__ L4 =
      (const float4*)((br ? Lu : Ld) + (size_t)row * NN + quarter * 1024);
  const float s1 = ws[S_OFF + (br ? 2*NN : 0) + row];
  const float* __restrict__ s2a = ws + S_OFF + (br ? 3*NN : NN);
  float4 lv[4];
  #pragma unroll
  for (int i = 0; i < 4; ++i) lv[i] = L4[i*64 + lane];

  unsigned long long m[16];
  int runs[16];
  int run = 0;
  #pragma unroll
  for (int i = 0; i < 4; ++i)
    #pragma unroll
    for (int c = 0; c < 4; ++c) {
      const int r = i*4 + c;
      m[r] = __ballot((&lv[i].x)[c] != 0.f);
      runs[r] = run;
      run += (int)__popcll(m[r]);
    }
  int base = 0;
  if (lane == 0 && run) base = atomicAdd(&cntbuf[br*NN + row], run);
  base = __shfl(base, 0);
  const size_t rb = (size_t)(br*NN + row) * CAP;
  const unsigned long long lmask = (1ull << lane) - 1ull;
  #pragma unroll
  for (int i = 0; i < 4; ++i)
    #pragma unroll
    for (int c = 0; c < 4; ++c) {
      const int r = i*4 + c;
      const float v = (&lv[i].x)[c];
      if (v != 0.f) {
        const int pos = base + runs[r] + (int)__popcll(m[r] & lmask);
        if (pos < CAP) {
          const int jj = quarter*1024 + (i*64 + lane)*4 + c;
          jbuf[rb + pos] = (unsigned)jj;
          valb[rb + pos] = v;
          const float sc = s1 + s2a[jj];
          eb[rb + pos] = expf(sc >= 0.f ? sc : SLOPE * sc);
        }
      }
    }
}

// ---------------------------------------------------------------------------
// Hx = L@x per row. One wave per row. readfirstlane pins the row to an SGPR
// so list loads are scalar; each gather is global_load_dwordx2.
__global__ __launch_bounds__(256) void k_gather_hx(
    const float* __restrict__ Ld, const float* __restrict__ Lu,
    const float* __restrict__ x, float* __restrict__ ws,
    const unsigned* __restrict__ jbuf, const float* __restrict__ valb,
    const int* __restrict__ cntbuf) {
  const int lane = threadIdx.x & 63;
  const int W = __builtin_amdgcn_readfirstlane(blockIdx.x * 4 + (threadIdx.x >> 6));
  const int br = W >> 12;
  const int row = W & (NN - 1);
  const float2* __restrict__ x2 = (const float2*)x;
  float2* __restrict__ Hx2 = (float2*)(ws + (br ? HXS_OFF : HXI_OFF));
  const int cnt = cntbuf[br*NN + row];
  float a0 = 0.f, a1 = 0.f;
  if (cnt <= CAP) {
    const unsigned* __restrict__ jb = jbuf + (size_t)(br*NN + row) * CAP;
    const float* __restrict__ vb = valb + (size_t)(br*NN + row) * CAP;
    int p = 0;
    for (; p + 8 <= cnt; p += 8) {
      unsigned j[8]; float wv[8]; float2 g[8];
      #pragma unroll
      for (int i = 0; i < 8; ++i) { j[i] = jb[p+i]; wv[i] = vb[p+i]; }
      #pragma unroll
      for (int i = 0; i < 8; ++i) g[i] = x2[(size_t)j[i]*64 + lane];
      #pragma unroll
      for (int i = 0; i < 8; ++i) { a0 += wv[i]*g[i].x; a1 += wv[i]*g[i].y; }
    }
    for (; p < cnt; ++p) {
      const float2 g = x2[(size_t)jb[p]*64 + lane];
      a0 += vb[p]*g.x; a1 += vb[p]*g.y;
    }
  } else {   // overflow fallback: dense rescan (essentially never taken)
    const float* __restrict__ Lrow = (br ? Lu : Ld) + (size_t)row * NN;
    for (int j = 0; j < NN; ++j) {
      const float v = Lrow[j];
      if (v != 0.f) { const float2 g = x2[(size_t)j*64 + lane]; a0 += v*g.x; a1 += v*g.y; }
    }
  }
  float2 o; o.x = a0; o.y = a1;
  Hx2[row*64 + lane] = o;
}

// ---------------------------------------------------------------------------
// Small GEMMs: U_irr = x@Wi0 + Hxi@Wi1 ; U_sol = x@Ws0 + Hxs@Ws1 ; xWh = x@Wh.
__global__ __launch_bounds__(256) void k_ugemm(
    const float* __restrict__ x, const float* __restrict__ Wi_w,
    const float* __restrict__ Ws_w, const float* __restrict__ Wh_w,
    float* __restrict__ ws) {
  const int rb = blockIdx.x;       // 128 row-blocks of 32
  const int sel = blockIdx.y;      // 0:U_irr 1:U_sol 2:xWh
  const float* A[2]; const float* W[2]; int npass; float* out;
  if (sel == 0)      { A[0]=x; W[0]=Wi_w; A[1]=ws+HXI_OFF; W[1]=Wi_w+16384; npass=2; out=ws+UI_OFF; }
  else if (sel == 1) { A[0]=x; W[0]=Ws_w; A[1]=ws+HXS_OFF; W[1]=Ws_w+16384; npass=2; out=ws+US_OFF; }
  else               { A[0]=x; W[0]=Wh_w; A[1]=nullptr;    W[1]=nullptr;    npass=1; out=ws+XWH_OFF; }

  __shared__ __align__(16) float At[32][33];
  __shared__ __align__(16) float Wt[32][132];
  const int t = threadIdx.x;
  const int rg = t >> 4, cg = t & 15;
  const int r0 = rb * 32;
  float acc[2][8];
  #pragma unroll
  for (int i = 0; i < 2; ++i)
    #pragma unroll
    for (int j = 0; j < 8; ++j) acc[i][j] = 0.f;

  for (int ps = 0; ps < npass; ++ps) {
    const float* __restrict__ Ap = A[ps];
    const float* __restrict__ Wp = W[ps];
    for (int k0 = 0; k0 < 128; k0 += 32) {
      __syncthreads();
      { const int row = t >> 3, kq = t & 7;
        const float4 av = *(const float4*)&Ap[(r0 + row)*128 + k0 + kq*4];
        At[row][kq*4+0] = av.x; At[row][kq*4+1] = av.y;
        At[row][kq*4+2] = av.z; At[row][kq*4+3] = av.w; }
      #pragma unroll
      for (int l = 0; l < 4; ++l) {
        const int idx = t + l*256;
        const int kr = idx >> 5, c4 = idx & 31;
        const float4 wv = *(const float4*)&Wp[(k0 + kr)*128 + c4*4];
        Wt[kr][c4*4+0] = wv.x; Wt[kr][c4*4+1] = wv.y;
        Wt[kr][c4*4+2] = wv.z; Wt[kr][c4*4+3] = wv.w;
      }
      __syncthreads();
      #pragma unroll
      for (int k = 0; k < 32; ++k) {
        const float a0 = At[rg*2 + 0][k];
        const float a1 = At[rg*2 + 1][k];
        const float4 b0 = *(const float4*)&Wt[k][cg*8];
        const float4 b1 = *(const float4*)&Wt[k][cg*8 + 4];
        acc[0][0] += a0*b0.x; acc[0][1] += a0*b0.y; acc[0][2] += a0*b0.z; acc[0][3] += a0*b0.w;
        acc[0][4] += a0*b1.x; acc[0][5] += a0*b1.y; acc[0][6] += a0*b1.z; acc[0][7] += a0*b1.w;
        acc[1][0] += a1*b0.x; acc[1][1] += a1*b0.y; acc[1][2] += a1*b0.z; acc[1][3] += a1*b0.w;
        acc[1][4] += a1*b1.x; acc[1][5] += a1*b1.y; acc[1][6] += a1*b1.z; acc[1][7] += a1*b1.w;
      }
    }
  }
  #pragma unroll
  for (int i = 0; i < 2; ++i) {
    const int r = r0 + rg*2 + i;
    #pragma unroll
    for (int j = 0; j < 8; ++j) out[r*128 + cg*8 + j] = acc[i][j];
  }
}

// ---------------------------------------------------------------------------
// Pack xWh (fp32 [4096k][128n]) into MFMA-fragment order, hi/lo bf16:
// Bp[f][n][8 shorts] = xWh[k=f*8..f*8+7][n], f = 0..511. A wave's B-load is
// then 256 B contiguous per quad (coalesced) instead of 16 lines at 8KB stride.
__global__ __launch_bounds__(256) void k_bpack(const float* __restrict__ ws,
                                               unsigned short* __restrict__ Bph,
                                               unsigned short* __restrict__ Bpl) {
  const float* __restrict__ Xw = ws + XWH_OFF;
  __shared__ float tile[64][129];
  const int t = threadIdx.x;
  const int k0 = blockIdx.x * 64;          // 64 k-blocks
  #pragma unroll
  for (int lp = 0; lp < 8; ++lp) {
    const int idx = t + lp*256;            // 2048 float4s = 64x128 floats
    const int r = idx >> 5, c4 = idx & 31;
    const float4 v = *(const float4*)&Xw[(size_t)(k0 + r)*128 + c4*4];
    tile[r][c4*4+0]=v.x; tile[r][c4*4+1]=v.y; tile[r][c4*4+2]=v.z; tile[r][c4*4+3]=v.w;
  }
  __syncthreads();
  const int n = t & 127, g = t >> 7;       // g = 0..1
  const int f0 = k0 >> 3;
  #pragma unroll
  for (int i = 0; i < 4; ++i) {
    const int fl = g*4 + i;                // local frag 0..7
    unsigned h[4], lo[4];
    #pragma unroll
    for (int q = 0; q < 4; ++q) {
      const float fa = tile[fl*8 + q*2][n], fb = tile[fl*8 + q*2 + 1][n];
      const unsigned ha = f2bf(fa), hb = f2bf(fb);
      h[q]  = ha | (hb << 16);
      lo[q] = f2bf(fa - bf2f(ha)) | (f2bf(fb - bf2f(hb)) << 16);
    }
    const size_t off = ((size_t)(f0 + fl)*128 + n) * 8;
    *(uint4*)&Bph[off] = make_uint4(h[0], h[1], h[2], h[3]);
    *(uint4*)&Bpl[off] = make_uint4(lo[0], lo[1], lo[2], lo[3]);
  }
}

// ---------------------------------------------------------------------------
// Dense P @ xWh on matrix cores, 3-term bf16 split, fragment-packed B.
// Block = 32 m x 128 n, 4 waves (wave = 16 m x 64 n, nt=4). Grid (128,8)
// = 1024 blocks = 4 blocks/CU = 16 waves/CU. Both A and B software-prefetched
// one K-iteration ahead; ~120 VGPR -> 4 waves/SIMD via __launch_bounds__(256,4).
__global__ __launch_bounds__(256, 4) void k_pgemm(const float* __restrict__ P,
                                               const unsigned short* __restrict__ Bph,
                                               const unsigned short* __restrict__ Bpl,
                                               float* __restrict__ zpart) {
  const int t = threadIdx.x;
  const int w = t >> 6, l = t & 63;
  const int quad = l >> 4, m16 = l & 15;
  const int mh = w >> 1, nh = w & 1;       // wave: m-half (0..1), n-half (0..1)
  const int r0 = blockIdx.x * 32;          // 128 m-blocks of 32
  const int kz = blockIdx.y;               // 8 K-splits of 512
  const int row = r0 + mh*16 + m16;
  const float* __restrict__ Arow = P + (size_t)row * NN;
  const int kbase = kz * 512;
  const int nb = nh*64 + m16;              // this lane's n within 0..127 (per nt: +nt*16)

  f32x4 acc[4];
  #pragma unroll
  for (int nt = 0; nt < 4; ++nt) acc[nt] = (f32x4){0.f, 0.f, 0.f, 0.f};

  // preload ks=0
  float4 a0 = *(const float4*)&Arow[kbase + quad*8];
  float4 a1 = *(const float4*)&Arow[kbase + quad*8 + 4];
  bf16x8 bh[4], bl[4];
  {
    const size_t fb = ((size_t)((kbase >> 3) + quad) * 128 + nb) * 8;
    #pragma unroll
    for (int nt = 0; nt < 4; ++nt) {
      bh[nt] = *(const bf16x8*)&Bph[fb + (size_t)nt*16*8];
      bl[nt] = *(const bf16x8*)&Bpl[fb + (size_t)nt*16*8];
    }
  }

  for (int ks = 0; ks < 16; ++ks) {
    // prefetch ks+1 (clamped on last iter; values discarded)
    const int k0n = kbase + ((ks + 1) & 15) * 32;
    const float4 na0 = *(const float4*)&Arow[k0n + quad*8];
    const float4 na1 = *(const float4*)&Arow[k0n + quad*8 + 4];
    bf16x8 nbh[4], nbl[4];
    const size_t fbn = ((size_t)((k0n >> 3) + quad) * 128 + nb) * 8;
    #pragma unroll
    for (int nt = 0; nt < 4; ++nt) {
      nbh[nt] = *(const bf16x8*)&Bph[fbn + (size_t)nt*16*8];
      nbl[nt] = *(const bf16x8*)&Bpl[fbn + (size_t)nt*16*8];
    }
    // convert current A to hi/lo bf16
    bf16x8 ah, al;
    #pragma unroll
    for (int c = 0; c < 4; ++c) {
      const float f0 = (&a0.x)[c], f1 = (&a1.x)[c];
      const unsigned h0 = f2bf(f0), h1 = f2bf(f1);
      ah[c]   = (short)h0; ah[c+4] = (short)h1;
      al[c]   = (short)f2bf(f0 - bf2f(h0));
      al[c+4] = (short)f2bf(f1 - bf2f(h1));
    }
    #pragma unroll
    for (int nt = 0; nt < 4; ++nt) {
      acc[nt] = __builtin_amdgcn_mfma_f32_16x16x32_bf16(ah, bh[nt], acc[nt], 0, 0, 0);
      acc[nt] = __builtin_amdgcn_mfma_f32_16x16x32_bf16(al, bh[nt], acc[nt], 0, 0, 0);
      acc[nt] = __builtin_amdgcn_mfma_f32_16x16x32_bf16(ah, bl[nt], acc[nt], 0, 0, 0);
    }
    a0 = na0; a1 = na1;
    #pragma unroll
    for (int nt = 0; nt < 4; ++nt) { bh[nt] = nbh[nt]; bl[nt] = nbl[nt]; }
  }
  float* __restrict__ zp = zpart + (size_t)kz * NN * 128;
  // C/D layout: col = lane&15, row = quad*4 + reg  [verified m89/m91]
  #pragma unroll
  for (int nt = 0; nt < 4; ++nt)
    #pragma unroll
    for (int r = 0; r < 4; ++r)
      zp[(size_t)(r0 + mh*16 + quad*4 + r)*128 + nh*64 + nt*16 + m16] = acc[nt][r];
}

// ---------------------------------------------------------------------------
// Attention: one wave per (row,branch). Scalar-load (j,e) lists, denominator
// accumulated in-register, 8 independent U-gathers in flight.
__global__ __launch_bounds__(256) void k_attn(
    const float* __restrict__ Ld, const float* __restrict__ Lu,
    float* __restrict__ ws, const unsigned* __restrict__ jbuf,
    const float* __restrict__ eb, const int* __restrict__ cntbuf) {
  const int lane = threadIdx.x & 63;
  const int W = __builtin_amdgcn_readfirstlane(blockIdx.x * 4 + (threadIdx.x >> 6));
  const int br = W >> 12;
  const int row = W & (NN - 1);
  const float2* __restrict__ U2 = (const float2*)(ws + (br ? US_OFF : UI_OFF));
  float2* __restrict__ O2 = (float2*)(ws + (br ? OS_OFF : OI_OFF));
  const int cnt = cntbuf[br*NN + row];
  float a0 = 0.f, a1 = 0.f, den = 0.f;

  if (cnt > 0 && cnt <= CAP) {
    const unsigned* __restrict__ jb = jbuf + (size_t)(br*NN + row) * CAP;
    const float* __restrict__ el = eb + (size_t)(br*NN + row) * CAP;
    int p = 0;
    for (; p + 8 <= cnt; p += 8) {
      unsigned j[8]; float e[8]; float2 g[8];
      #pragma unroll
      for (int i = 0; i < 8; ++i) { j[i] = jb[p+i]; e[i] = el[p+i]; }
      #pragma unroll
      for (int i = 0; i < 8; ++i) g[i] = U2[(size_t)j[i]*64 + lane];
      #pragma unroll
      for (int i = 0; i < 8; ++i) { a0 += e[i]*g[i].x; a1 += e[i]*g[i].y; den += e[i]; }
    }
    for (; p < cnt; ++p) {
      const float2 g = U2[(size_t)jb[p]*64 + lane];
      a0 += el[p]*g.x; a1 += el[p]*g.y; den += el[p];
    }
    float2 o; o.x = a0 / den; o.y = a1 / den;
    O2[row*64 + lane] = o;
  } else if (cnt == 0) {
    // all-masked row -> uniform softmax (never taken at 5% density)
    for (int j = 0; j < NN; ++j) { const float2 g = U2[(size_t)j*64 + lane]; a0 += g.x; a1 += g.y; }
    float2 o; o.x = a0 * (1.f/NN); o.y = a1 * (1.f/NN);
    O2[row*64 + lane] = o;
  } else {
    // list overflow fallback: dense rescan with on-the-fly scores
    const float s1 = ws[S_OFF + (br ? 2*NN : 0) + row];
    const float* __restrict__ s2a = ws + S_OFF + (br ? 3*NN : NN);
    const float* __restrict__ Lrow = (br ? Lu : Ld) + (size_t)row * NN;
    for (int j = 0; j < NN; ++j) {
      const float v = Lrow[j];
      if (v != 0.f) {
        const float sc = s1 + s2a[j];
        const float e = expf(sc >= 0.f ? sc : SLOPE * sc);
        const float2 g = U2[(size_t)j*64 + lane];
        a0 += e*g.x; a1 += e*g.y; den += e;
      }
    }
    float2 o; o.x = a0 / den; o.y = a1 / den;
    O2[row*64 + lane] = o;
  }
}

// ---------------------------------------------------------------------------
// z = O_irr + O_sol + sum_k zpart[k] + b_total
__global__ __launch_bounds__(256) void k_combine(const float* __restrict__ ws,
                                                 float* __restrict__ z) {
  const int i = blockIdx.x * 256 + threadIdx.x;
  const int col = i & 127;
  float acc = ws[BT_OFF + col] + ws[OI_OFF + i] + ws[OS_OFF + i];
  #pragma unroll
  for (int kz = 0; kz < 8; ++kz) acc += ws[ZP_OFF + kz*NN*128 + i];
  z[i] = acc;
}

// ---------------------------------------------------------------------------
extern "C" void kernel_launch(void* const* d_in, const int* in_sizes, int n_in,
                              void* d_out, int out_size, void* d_ws, size_t ws_size,
                              hipStream_t stream) {
  const float* x       = (const float*)d_in[0];
  const float* Lu      = (const float*)d_in[1];
  const float* Ld      = (const float*)d_in[2];
  const float* P       = (const float*)d_in[3];
  const float* Wi_w    = (const float*)d_in[4];
  const float* Wi_b    = (const float*)d_in[5];
  const float* Ws_w    = (const float*)d_in[6];
  const float* Ws_b    = (const float*)d_in[7];
  const float* Wh_w    = (const float*)d_in[8];
  const float* Wh_b    = (const float*)d_in[9];
  const float* att_irr = (const float*)d_in[10];
  const float* att_sol = (const float*)d_in[11];
  float* z  = (float*)d_out;
  float* ws = (float*)d_ws;
  unsigned*       jbuf = (unsigned*)((char*)d_ws + JB_BYTE_OFF);
  float*          valb = (float*)((char*)d_ws + VB_BYTE_OFF);
  float*          ebuf = (float*)((char*)d_ws + EB_BYTE_OFF);
  int*            cntb = (int*)((char*)d_ws + CNT_BYTE_OFF);
  unsigned short* bph  = (unsigned short*)((char*)d_ws + BPH_BYTE_OFF);
  unsigned short* bpl  = (unsigned short*)((char*)d_ws + BPL_BYTE_OFF);

  k_prep<<<1, 128, 0, stream>>>(Wi_w, Wi_b, Ws_w, Ws_b, Wh_b, att_irr, att_sol, ws);
  k_scores<<<1024, 256, 0, stream>>>(x, ws);
  k_zero<<<32, 256, 0, stream>>>(cntb);
  k_csr<<<8192, 256, 0, stream>>>(Ld, Lu, ws, cntb, jbuf, valb, ebuf);
  k_gather_hx<<<2048, 256, 0, stream>>>(Ld, Lu, x, ws, jbuf, valb, cntb);
  {
    dim3 g(128, 3);
    k_ugemm<<<g, 256, 0, stream>>>(x, Wi_w, Ws_w, Wh_w, ws);
  }
  k_bpack<<<64, 256, 0, stream>>>(ws, bph, bpl);
  {
    dim3 g(128, 8);
    k_pgemm<<<g, 256, 0, stream>>>(P, bph, bpl, ws + ZP_OFF);
  }
  k_attn<<<2048, 256, 0, stream>>>(Ld, Lu, ws, jbuf, ebuf, cntb);
  k_combine<<<NN * 128 / 256, 256, 0, stream>>>(ws, z);
}